// Round 2
// baseline (53.665 us; speedup 1.0000x reference)
//
#include <hip/hip_runtime.h>

#define TPB     128
#define PERSONS 128
#define ROW     45   // 15 joints * 3 dims
#define KJ      15

__global__ __launch_bounds__(TPB) void limb_kernel(const float* __restrict__ in,
                                                   float* __restrict__ out, int B) {
    __shared__ float lds[PERSONS * ROW];  // 23,040 B -> 7 blocks/CU
    const int tid = threadIdx.x;
    const long long bstart = (long long)blockIdx.x * PERSONS;
    const int npersons = (int)min((long long)PERSONS, (long long)B - bstart);
    const long long fbase = bstart * ROW;  // 23040*bid bytes -> 16B aligned

    // ---- coalesced global -> LDS staging (float4) ----
    const int F  = npersons * ROW;
    const int Fv = F >> 2;                 // float4 count
    const float4* __restrict__ src4 = (const float4*)(in + fbase);
    float4* lds4 = (float4*)lds;
    for (int idx = tid; idx < Fv; idx += TPB) lds4[idx] = src4[idx];
    for (int idx = (Fv << 2) + tid; idx < F; idx += TPB) lds[idx] = in[fbase + idx];
    __syncthreads();   // the only barrier

    // ---- per-person compute from LDS (lane stride 45: coprime w/ 32 banks,
    //      conflict-free), direct scalar stores (L2 merges into full lines) ----
    if (tid < npersons) {
        const float* s = &lds[tid * ROW];
        float x[KJ], y[KJ], z[KJ];
        #pragma unroll
        for (int k = 0; k < KJ; ++k) {     // exactly 45 ds_read_b32, no re-reads
            x[k] = s[k * 3 + 0];
            y[k] = s[k * 3 + 1];
            z[k] = s[k * 3 + 2];
        }
        const int conn[KJ] = {0, 0, 1, 1, 1, 3, 4, 5, 6, 2, 2, 9, 10, 11, 12};
        float* o = out + (bstart + tid) * KJ;
        #pragma unroll
        for (int k = 0; k < KJ; ++k) {
            const int c = conn[k];
            const float dx = x[k] - x[c];
            const float dy = y[k] - y[c];
            const float dz = z[k] - z[c];
            o[k] = sqrtf(dx * dx + dy * dy + dz * dz);
        }
    }
}

extern "C" void kernel_launch(void* const* d_in, const int* in_sizes, int n_in,
                              void* d_out, int out_size, void* d_ws, size_t ws_size,
                              hipStream_t stream) {
    const float* in = (const float*)d_in[0];
    float* out = (float*)d_out;
    const int B = in_sizes[0] / ROW;           // 1,000,000
    const int grid = (B + PERSONS - 1) / PERSONS;
    limb_kernel<<<grid, TPB, 0, stream>>>(in, out, B);
}

// Round 3
// 39.278 us; speedup vs baseline: 1.3663x; 1.3663x over previous
//
#include <hip/hip_runtime.h>

#define KJ 15

__global__ __launch_bounds__(256) void limb_kernel(const float* __restrict__ in,
                                                   float* __restrict__ out, int B) {
    const int lane = threadIdx.x & 63;
    const int wib  = threadIdx.x >> 6;
    const int nwaves = gridDim.x * (blockDim.x >> 6);
    const int gw = blockIdx.x * (blockDim.x >> 6) + wib;

    const int sub = lane / 15;          // person-within-wave 0..3 (lanes 60-63 -> 4, masked)
    const int k   = lane - sub * 15;    // joint id 0..14
    const bool active = (lane < 60);

    // conn[k] from packed nibbles: {0,0,1,1,1,3,4,5,6,2,2,9,10,11,12}
    const unsigned lo = 0x54311100u, hi = 0x0CBA9226u;
    const int c = (int)(((k < 8) ? (lo >> (k * 4)) : (hi >> ((k - 8) * 4))) & 0xFu);
    const int bperm = (sub * KJ + c) << 2;   // byte index of source lane (wave-local)

    // grid-stride over person-groups of 8 (two 4-person half-groups per iter for MLP)
    for (int pg = gw; pg * 8 < B; pg += nwaves) {
        const int pA = pg * 8 + sub;
        const int pB = pA + 4;
        const bool okA = active && (pA < B);
        const bool okB = active && (pB < B);
        // safe-address trick keeps all lanes converged through the bpermutes
        const float* sA = in + (okA ? (pA * 45 + k * 3) : 0);
        const float* sB = in + (okB ? (pB * 45 + k * 3) : 0);
        const float xA = sA[0], yA = sA[1], zA = sA[2];
        const float xB = sB[0], yB = sB[1], zB = sB[2];

        const float cxA = __int_as_float(__builtin_amdgcn_ds_bpermute(bperm, __float_as_int(xA)));
        const float cyA = __int_as_float(__builtin_amdgcn_ds_bpermute(bperm, __float_as_int(yA)));
        const float czA = __int_as_float(__builtin_amdgcn_ds_bpermute(bperm, __float_as_int(zA)));
        const float cxB = __int_as_float(__builtin_amdgcn_ds_bpermute(bperm, __float_as_int(xB)));
        const float cyB = __int_as_float(__builtin_amdgcn_ds_bpermute(bperm, __float_as_int(yB)));
        const float czB = __int_as_float(__builtin_amdgcn_ds_bpermute(bperm, __float_as_int(zB)));

        if (okA) {
            const float dx = xA - cxA, dy = yA - cyA, dz = zA - czA;
            out[pA * KJ + k] = sqrtf(dx * dx + dy * dy + dz * dz);  // = pg*120 + lane: coalesced
        }
        if (okB) {
            const float dx = xB - cxB, dy = yB - cyB, dz = zB - czB;
            out[pB * KJ + k] = sqrtf(dx * dx + dy * dy + dz * dz);
        }
    }
}

extern "C" void kernel_launch(void* const* d_in, const int* in_sizes, int n_in,
                              void* d_out, int out_size, void* d_ws, size_t ws_size,
                              hipStream_t stream) {
    const float* in = (const float*)d_in[0];
    float* out = (float*)d_out;
    const int B = in_sizes[0] / 45;            // 1,000,000 persons
    limb_kernel<<<2048, 256, 0, stream>>>(in, out, B);
}